// Round 1
// baseline (1366.399 us; speedup 1.0000x reference)
//
#include <hip/hip_runtime.h>
#include <math.h>

#define BB 2
#define CC 256
#define LL 4096
#define NL (BB*LL)
#define DI 512
#define DTR 16
#define DS 16
#define NPROJ 48
#define SCH 64

// ---------------- LN1: x (B,C,L) -> h (B,L,C) normalized over C ----------------
__global__ __launch_bounds__(256) void ln1_kernel(const float* __restrict__ x,
    const float* __restrict__ w, const float* __restrict__ bias, float* __restrict__ h) {
  int blk = blockIdx.x;
  int b = blk / (LL / 16);
  int l0 = (blk % (LL / 16)) * 16;
  int tid = threadIdx.x;
  int li = tid & 15, ci = tid >> 4;
  __shared__ float tile[CC][17];
  __shared__ float rs[16][17], rs2[16][17];
  __shared__ float mu[16], rstd[16];
  const float* xb = x + (size_t)b * CC * LL;
  #pragma unroll
  for (int c0 = 0; c0 < CC; c0 += 16)
    tile[c0 + ci][li] = xb[(size_t)(c0 + ci) * LL + l0 + li];
  __syncthreads();
  float s = 0.f, s2 = 0.f;
  #pragma unroll
  for (int j = 0; j < 16; ++j) {
    float v = tile[ci * 16 + j][li];
    s += v; s2 += v * v;
  }
  rs[li][ci] = s; rs2[li][ci] = s2;
  __syncthreads();
  if (ci == 0) {
    float a = 0.f, a2 = 0.f;
    #pragma unroll
    for (int j = 0; j < 16; ++j) { a += rs[li][j]; a2 += rs2[li][j]; }
    float m = a * (1.f / CC);
    float var = a2 * (1.f / CC) - m * m;
    mu[li] = m; rstd[li] = rsqrtf(var + 1e-5f);
  }
  __syncthreads();
  int ci2 = tid & 15, li2 = tid >> 4;
  float* hb = h + (size_t)(b * LL + l0) * CC;
  #pragma unroll
  for (int c0 = 0; c0 < CC; c0 += 16) {
    int c = c0 + ci2;
    float v = tile[c][li2];
    hb[(size_t)li2 * CC + c] = (v - mu[li2]) * rstd[li2] * w[c] + bias[c];
  }
}

// --------- generic fp32 GEMM: C[M,N] = A[M,K] @ B[N,K]^T, 64x64 tiles ---------
__global__ __launch_bounds__(256) void gemm_nt(const float* __restrict__ A,
    const float* __restrict__ B, float* __restrict__ C, int M, int N, int K) {
  __shared__ float As[16][68], Bs[16][68];
  int m0 = blockIdx.y * 64, n0 = blockIdx.x * 64;
  int tid = threadIdx.x;
  int lr = tid >> 2, lc = (tid & 3) * 4;
  int tx = tid & 15, ty = tid >> 4;
  float acc[4][4] = {{0.f}};
  for (int k0 = 0; k0 < K; k0 += 16) {
    float4 av = *(const float4*)&A[(size_t)(m0 + lr) * K + k0 + lc];
    float4 bv = *(const float4*)&B[(size_t)(n0 + lr) * K + k0 + lc];
    As[lc + 0][lr] = av.x; As[lc + 1][lr] = av.y; As[lc + 2][lr] = av.z; As[lc + 3][lr] = av.w;
    Bs[lc + 0][lr] = bv.x; Bs[lc + 1][lr] = bv.y; Bs[lc + 2][lr] = bv.z; Bs[lc + 3][lr] = bv.w;
    __syncthreads();
    #pragma unroll
    for (int kk = 0; kk < 16; ++kk) {
      float a[4], bb[4];
      #pragma unroll
      for (int i = 0; i < 4; ++i) a[i] = As[kk][ty * 4 + i];
      #pragma unroll
      for (int j = 0; j < 4; ++j) bb[j] = Bs[kk][tx * 4 + j];
      #pragma unroll
      for (int i = 0; i < 4; ++i)
        #pragma unroll
        for (int j = 0; j < 4; ++j)
          acc[i][j] += a[i] * bb[j];
    }
    __syncthreads();
  }
  #pragma unroll
  for (int i = 0; i < 4; ++i) {
    float4 o = make_float4(acc[i][0], acc[i][1], acc[i][2], acc[i][3]);
    *(float4*)&C[(size_t)(m0 + ty * 4 + i) * N + n0 + tx * 4] = o;
  }
}

// ------------- depthwise causal conv (k=4) + bias + SiLU -------------
__global__ __launch_bounds__(512) void conv_silu_kernel(const float* __restrict__ xz,
    const float* __restrict__ cw, const float* __restrict__ cb, float* __restrict__ xc) {
  int blk = blockIdx.x;            // b*LL + l
  int b = blk / LL, l = blk % LL;
  int d = threadIdx.x;             // 512
  const float4 w4 = *(const float4*)&cw[d * 4];
  const float* base = xz + (size_t)b * LL * 1024 + d;
  float s = cb[d];
  if (l >= 3) s += base[(size_t)(l - 3) * 1024] * w4.x;
  if (l >= 2) s += base[(size_t)(l - 2) * 1024] * w4.y;
  if (l >= 1) s += base[(size_t)(l - 1) * 1024] * w4.z;
  s += base[(size_t)l * 1024] * w4.w;
  xc[(size_t)blk * DI + d] = s / (1.f + __expf(-s));
}

// ------------- transpose x_proj_w (48,512) -> (512,48) -------------
__global__ void transpose_xpw(const float* __restrict__ src, float* __restrict__ dst) {
  int idx = blockIdx.x * 256 + threadIdx.x;
  if (idx < NPROJ * DI) {
    int j = idx / DI, k = idx % DI;
    dst[k * NPROJ + j] = src[idx];
  }
}

// ------------- x_proj: proj (NL,48) = xc (NL,512) @ Wt (512,48) -------------
__global__ __launch_bounds__(256) void xproj_kernel(const float* __restrict__ xc,
    const float* __restrict__ wt, float* __restrict__ proj) {
  int r0 = blockIdx.x * 16;
  int tid = threadIdx.x;
  __shared__ float xs[16][DI];
  for (int i = tid; i < 16 * (DI / 4); i += 256) {
    int row = i / (DI / 4);
    int c4 = (i % (DI / 4)) * 4;
    *(float4*)&xs[row][c4] = *(const float4*)&xc[(size_t)(r0 + row) * DI + c4];
  }
  __syncthreads();
  for (int o = tid; o < 16 * NPROJ; o += 256) {
    int row = o / NPROJ, j = o % NPROJ;
    float acc = 0.f;
    for (int k = 0; k < DI; ++k)
      acc += xs[row][k] * wt[k * NPROJ + j];
    proj[(size_t)(r0 + row) * NPROJ + j] = acc;
  }
}

// ------------- dt = softplus(proj[:, :16] @ dtw^T + dtb) -------------
__global__ __launch_bounds__(512) void dt_kernel(const float* __restrict__ proj,
    const float* __restrict__ dtw, const float* __restrict__ dtbias, float* __restrict__ dt) {
  int row = blockIdx.x;
  int d = threadIdx.x;
  __shared__ float pr[DTR];
  if (d < DTR) pr[d] = proj[(size_t)row * NPROJ + d];
  __syncthreads();
  float acc = dtbias[d];
  const float4* wr = (const float4*)&dtw[d * DTR];
  #pragma unroll
  for (int r4 = 0; r4 < 4; ++r4) {
    float4 w4 = wr[r4];
    acc += pr[r4 * 4 + 0] * w4.x + pr[r4 * 4 + 1] * w4.y
         + pr[r4 * 4 + 2] * w4.z + pr[r4 * 4 + 3] * w4.w;
  }
  float sp = (acc > 20.f) ? acc : log1pf(__expf(acc));
  dt[(size_t)row * DI + d] = sp;
}

// ------------- selective scan + D skip + z gate -------------
// block = 256 threads = 16 d x 16 s; grid = (DI/16, B)
__global__ __launch_bounds__(256) void scan_kernel(const float* __restrict__ dt,
    const float* __restrict__ xc, const float* __restrict__ xz,
    const float* __restrict__ proj, const float* __restrict__ A_log,
    const float* __restrict__ Dv, float* __restrict__ y) {
  int d0 = blockIdx.x * 16;
  int b = blockIdx.y;
  int tid = threadIdx.x;
  int s = tid & 15, dl = tid >> 4;
  int d = d0 + dl;
  float Aval = -__expf(A_log[d * DS + s]);
  float Dd = Dv[d];
  __shared__ float dtc[SCH][16], xcv[SCH][16], zc[SCH][16], Bc[SCH][16], Cc[SCH][16], ybuf[SCH][16];
  float hst = 0.f;
  int row_l = tid >> 2;
  int q4 = (tid & 3) * 4;
  for (int c0 = 0; c0 < LL; c0 += SCH) {
    size_t rb = (size_t)(b * LL + c0 + row_l);
    *(float4*)&dtc[row_l][q4] = *(const float4*)&dt[rb * DI + d0 + q4];
    *(float4*)&xcv[row_l][q4] = *(const float4*)&xc[rb * DI + d0 + q4];
    *(float4*)&zc[row_l][q4]  = *(const float4*)&xz[rb * 1024 + DI + d0 + q4];
    *(float4*)&Bc[row_l][q4]  = *(const float4*)&proj[rb * NPROJ + DTR + q4];
    *(float4*)&Cc[row_l][q4]  = *(const float4*)&proj[rb * NPROJ + DTR + DS + q4];
    __syncthreads();
    for (int j = 0; j < SCH; ++j) {
      float dtv = dtc[j][dl];
      float xv  = xcv[j][dl];
      float dA  = __expf(dtv * Aval);
      hst = hst * dA + dtv * xv * Bc[j][s];
      float contrib = hst * Cc[j][s];
      contrib += __shfl_xor(contrib, 1);
      contrib += __shfl_xor(contrib, 2);
      contrib += __shfl_xor(contrib, 4);
      contrib += __shfl_xor(contrib, 8);
      if (s == 0) {
        float zv = zc[j][dl];
        ybuf[j][dl] = (contrib + xv * Dd) * (zv / (1.f + __expf(-zv)));
      }
    }
    __syncthreads();
    *(float4*)&y[rb * DI + d0 + q4] = *(const float4*)&ybuf[row_l][q4];
  }
}

// ------------- LN2 + residual, (B,L,C) -> out (B,C,L) -------------
__global__ __launch_bounds__(256) void ln2_res_kernel(const float* __restrict__ mo,
    const float* __restrict__ x, const float* __restrict__ w, const float* __restrict__ bias,
    float* __restrict__ out) {
  int blk = blockIdx.x;
  int b = blk / (LL / 16);
  int l0 = (blk % (LL / 16)) * 16;
  int tid = threadIdx.x;
  __shared__ float tile[16][CC + 1];
  __shared__ float rs[16][17], rs2[16][17];
  __shared__ float mu[16], rstd[16];
  int ci2 = tid & 15, li2 = tid >> 4;
  const float* mb = mo + (size_t)(b * LL + l0) * CC;
  #pragma unroll
  for (int c0 = 0; c0 < CC; c0 += 16)
    tile[li2][c0 + ci2] = mb[(size_t)li2 * CC + c0 + ci2];
  __syncthreads();
  int li = tid & 15, ci = tid >> 4;
  float s = 0.f, s2 = 0.f;
  #pragma unroll
  for (int j = 0; j < 16; ++j) {
    float v = tile[li][ci * 16 + j];
    s += v; s2 += v * v;
  }
  rs[li][ci] = s; rs2[li][ci] = s2;
  __syncthreads();
  if (ci == 0) {
    float a = 0.f, a2 = 0.f;
    #pragma unroll
    for (int j = 0; j < 16; ++j) { a += rs[li][j]; a2 += rs2[li][j]; }
    float m = a * (1.f / CC);
    float var = a2 * (1.f / CC) - m * m;
    mu[li] = m; rstd[li] = rsqrtf(var + 1e-5f);
  }
  __syncthreads();
  int wli = tid & 15, wci = tid >> 4;
  const float* xb = x + (size_t)b * CC * LL;
  float* ob = out + (size_t)b * CC * LL;
  #pragma unroll
  for (int c0 = 0; c0 < CC; c0 += 16) {
    int c = c0 + wci;
    size_t idx = (size_t)c * LL + l0 + wli;
    float v = tile[wli][c];
    ob[idx] = xb[idx] + (v - mu[wli]) * rstd[wli] * w[c] + bias[c];
  }
}

extern "C" void kernel_launch(void* const* d_in, const int* in_sizes, int n_in,
                              void* d_out, int out_size, void* d_ws, size_t ws_size,
                              hipStream_t stream) {
  const float* x         = (const float*)d_in[0];
  const float* ln1_w     = (const float*)d_in[1];
  const float* ln1_b     = (const float*)d_in[2];
  const float* ln2_w     = (const float*)d_in[3];
  const float* ln2_b     = (const float*)d_in[4];
  const float* in_proj_w = (const float*)d_in[5];
  const float* conv_w    = (const float*)d_in[6];
  const float* conv_b    = (const float*)d_in[7];
  const float* x_proj_w  = (const float*)d_in[8];
  const float* dt_proj_w = (const float*)d_in[9];
  const float* dt_proj_b = (const float*)d_in[10];
  const float* A_log     = (const float*)d_in[11];
  const float* Dv        = (const float*)d_in[12];
  const float* out_proj_w= (const float*)d_in[13];

  float* ws   = (float*)d_ws;
  float* h    = ws;                         // NL*256
  float* xz   = h + (size_t)NL * CC;        // NL*1024 (xm | z)
  float* xc   = xz + (size_t)NL * 1024;     // NL*512
  float* proj = xc + (size_t)NL * DI;       // NL*48
  float* dtb  = proj + (size_t)NL * NPROJ;  // NL*512
  float* y    = dtb + (size_t)NL * DI;      // NL*512
  float* xpwt = y + (size_t)NL * DI;        // 512*48
  float* mo   = h;                          // reuse h (dead after gemm1)

  ln1_kernel<<<NL / 16, 256, 0, stream>>>(x, ln1_w, ln1_b, h);
  gemm_nt<<<dim3(1024 / 64, NL / 64), 256, 0, stream>>>(h, in_proj_w, xz, NL, 1024, 256);
  conv_silu_kernel<<<NL, 512, 0, stream>>>(xz, conv_w, conv_b, xc);
  transpose_xpw<<<(NPROJ * DI + 255) / 256, 256, 0, stream>>>(x_proj_w, xpwt);
  xproj_kernel<<<NL / 16, 256, 0, stream>>>(xc, xpwt, proj);
  dt_kernel<<<NL, 512, 0, stream>>>(proj, dt_proj_w, dt_proj_b, dtb);
  scan_kernel<<<dim3(DI / 16, BB), 256, 0, stream>>>(dtb, xc, xz, proj, A_log, Dv, y);
  gemm_nt<<<dim3(256 / 64, NL / 64), 256, 0, stream>>>(y, out_proj_w, mo, NL, 256, 512);
  ln2_res_kernel<<<NL / 16, 256, 0, stream>>>(mo, x, ln2_w, ln2_b, (float*)d_out);
}

// Round 2
// 332.397 us; speedup vs baseline: 4.1107x; 4.1107x over previous
//
#include <hip/hip_runtime.h>
#include <math.h>

#define BB 2
#define CC 256
#define LL 4096
#define NL (BB*LL)
#define DI 512
#define DTR 16
#define DS 16
#define NPROJ 48
#define G_CHUNK 128
#define LC (LL / G_CHUNK)   // 32 steps per chunk

// ---------------- LN1: x (B,C,L) -> h (B,L,C) normalized over C ----------------
__global__ __launch_bounds__(256) void ln1_kernel(const float* __restrict__ x,
    const float* __restrict__ w, const float* __restrict__ bias, float* __restrict__ h) {
  int blk = blockIdx.x;
  int b = blk / (LL / 16);
  int l0 = (blk % (LL / 16)) * 16;
  int tid = threadIdx.x;
  int li = tid & 15, ci = tid >> 4;
  __shared__ float tile[CC][17];
  __shared__ float rs[16][17], rs2[16][17];
  __shared__ float mu[16], rstd[16];
  const float* xb = x + (size_t)b * CC * LL;
  #pragma unroll
  for (int c0 = 0; c0 < CC; c0 += 16)
    tile[c0 + ci][li] = xb[(size_t)(c0 + ci) * LL + l0 + li];
  __syncthreads();
  float s = 0.f, s2 = 0.f;
  #pragma unroll
  for (int j = 0; j < 16; ++j) {
    float v = tile[ci * 16 + j][li];
    s += v; s2 += v * v;
  }
  rs[li][ci] = s; rs2[li][ci] = s2;
  __syncthreads();
  if (ci == 0) {
    float a = 0.f, a2 = 0.f;
    #pragma unroll
    for (int j = 0; j < 16; ++j) { a += rs[li][j]; a2 += rs2[li][j]; }
    float m = a * (1.f / CC);
    float var = a2 * (1.f / CC) - m * m;
    mu[li] = m; rstd[li] = rsqrtf(var + 1e-5f);
  }
  __syncthreads();
  int ci2 = tid & 15, li2 = tid >> 4;
  float* hb = h + (size_t)(b * LL + l0) * CC;
  #pragma unroll
  for (int c0 = 0; c0 < CC; c0 += 16) {
    int c = c0 + ci2;
    float v = tile[c][li2];
    hb[(size_t)li2 * CC + c] = (v - mu[li2]) * rstd[li2] * w[c] + bias[c];
  }
}

// --------- generic fp32 GEMM: C[M,N] = A[M,K] @ B[N,K]^T, 64x64 tiles ---------
__global__ __launch_bounds__(256) void gemm_nt(const float* __restrict__ A,
    const float* __restrict__ B, float* __restrict__ C, int M, int N, int K) {
  __shared__ float As[16][68], Bs[16][68];
  int m0 = blockIdx.y * 64, n0 = blockIdx.x * 64;
  int tid = threadIdx.x;
  int lr = tid >> 2, lc = (tid & 3) * 4;
  int tx = tid & 15, ty = tid >> 4;
  float acc[4][4] = {{0.f}};
  for (int k0 = 0; k0 < K; k0 += 16) {
    float4 av = *(const float4*)&A[(size_t)(m0 + lr) * K + k0 + lc];
    float4 bv = *(const float4*)&B[(size_t)(n0 + lr) * K + k0 + lc];
    As[lc + 0][lr] = av.x; As[lc + 1][lr] = av.y; As[lc + 2][lr] = av.z; As[lc + 3][lr] = av.w;
    Bs[lc + 0][lr] = bv.x; Bs[lc + 1][lr] = bv.y; Bs[lc + 2][lr] = bv.z; Bs[lc + 3][lr] = bv.w;
    __syncthreads();
    #pragma unroll
    for (int kk = 0; kk < 16; ++kk) {
      float a[4], bb[4];
      #pragma unroll
      for (int i = 0; i < 4; ++i) a[i] = As[kk][ty * 4 + i];
      #pragma unroll
      for (int j = 0; j < 4; ++j) bb[j] = Bs[kk][tx * 4 + j];
      #pragma unroll
      for (int i = 0; i < 4; ++i)
        #pragma unroll
        for (int j = 0; j < 4; ++j)
          acc[i][j] += a[i] * bb[j];
    }
    __syncthreads();
  }
  #pragma unroll
  for (int i = 0; i < 4; ++i) {
    float4 o = make_float4(acc[i][0], acc[i][1], acc[i][2], acc[i][3]);
    *(float4*)&C[(size_t)(m0 + ty * 4 + i) * N + n0 + tx * 4] = o;
  }
}

// ------------- depthwise causal conv (k=4) + bias + SiLU -------------
__global__ __launch_bounds__(512) void conv_silu_kernel(const float* __restrict__ xz,
    const float* __restrict__ cw, const float* __restrict__ cb, float* __restrict__ xc) {
  int blk = blockIdx.x;            // b*LL + l
  int b = blk / LL, l = blk % LL;
  int d = threadIdx.x;             // 512
  const float4 w4 = *(const float4*)&cw[d * 4];
  const float* base = xz + (size_t)b * LL * 1024 + d;
  float s = cb[d];
  if (l >= 3) s += base[(size_t)(l - 3) * 1024] * w4.x;
  if (l >= 2) s += base[(size_t)(l - 2) * 1024] * w4.y;
  if (l >= 1) s += base[(size_t)(l - 1) * 1024] * w4.z;
  s += base[(size_t)l * 1024] * w4.w;
  xc[(size_t)blk * DI + d] = s / (1.f + __expf(-s));
}

// ------------- transpose x_proj_w (48,512) -> (512,48) -------------
__global__ void transpose_xpw(const float* __restrict__ src, float* __restrict__ dst) {
  int idx = blockIdx.x * 256 + threadIdx.x;
  if (idx < NPROJ * DI) {
    int j = idx / DI, k = idx % DI;
    dst[k * NPROJ + j] = src[idx];
  }
}

// ------------- x_proj: proj (NL,48) = xc (NL,512) @ Wt (512,48) -------------
__global__ __launch_bounds__(256) void xproj_kernel(const float* __restrict__ xc,
    const float* __restrict__ wt, float* __restrict__ proj) {
  int r0 = blockIdx.x * 16;
  int tid = threadIdx.x;
  __shared__ float xs[16][DI];
  for (int i = tid; i < 16 * (DI / 4); i += 256) {
    int row = i / (DI / 4);
    int c4 = (i % (DI / 4)) * 4;
    *(float4*)&xs[row][c4] = *(const float4*)&xc[(size_t)(r0 + row) * DI + c4];
  }
  __syncthreads();
  for (int o = tid; o < 16 * NPROJ; o += 256) {
    int row = o / NPROJ, j = o % NPROJ;
    float acc = 0.f;
    for (int k = 0; k < DI; ++k)
      acc += xs[row][k] * wt[k * NPROJ + j];
    proj[(size_t)(r0 + row) * NPROJ + j] = acc;
  }
}

// ------------- dt = softplus(proj[:, :16] @ dtw^T + dtb) -------------
__global__ __launch_bounds__(512) void dt_kernel(const float* __restrict__ proj,
    const float* __restrict__ dtw, const float* __restrict__ dtbias, float* __restrict__ dt) {
  int row = blockIdx.x;
  int d = threadIdx.x;
  __shared__ float pr[DTR];
  if (d < DTR) pr[d] = proj[(size_t)row * NPROJ + d];
  __syncthreads();
  float acc = dtbias[d];
  const float4* wr = (const float4*)&dtw[d * DTR];
  #pragma unroll
  for (int r4 = 0; r4 < 4; ++r4) {
    float4 w4 = wr[r4];
    acc += pr[r4 * 4 + 0] * w4.x + pr[r4 * 4 + 1] * w4.y
         + pr[r4 * 4 + 2] * w4.z + pr[r4 * 4 + 3] * w4.w;
  }
  float sp = (acc > 20.f) ? acc : log1pf(__expf(acc));
  dt[(size_t)row * DI + d] = sp;
}

// ===================== chunk-parallel selective scan =====================
// Pass A: per (b, d, chunk) one lane: local scan from h0=0 over LC steps.
// Outputs hend[b][g][d][16] and sdt[b][g][d] (sum of dt over chunk).
__global__ __launch_bounds__(512) void scan_passA(const float* __restrict__ dt,
    const float* __restrict__ xc, const float* __restrict__ proj,
    const float* __restrict__ A_log, float* __restrict__ hend,
    float* __restrict__ sdt_out) {
  int g = blockIdx.x, b = blockIdx.y;
  int d = threadIdx.x;
  int t0 = g * LC;
  __shared__ float Bs[LC][16];
  int tid = threadIdx.x;
  if (tid < LC * 4) {
    int row = tid >> 2, q = (tid & 3) * 4;
    *(float4*)&Bs[row][q] =
        *(const float4*)&proj[(size_t)(b * LL + t0 + row) * NPROJ + DTR + q];
  }
  float As[16];
  #pragma unroll
  for (int s4 = 0; s4 < 4; ++s4) {
    float4 a4 = *(const float4*)&A_log[d * DS + s4 * 4];
    As[s4 * 4 + 0] = -__expf(a4.x);
    As[s4 * 4 + 1] = -__expf(a4.y);
    As[s4 * 4 + 2] = -__expf(a4.z);
    As[s4 * 4 + 3] = -__expf(a4.w);
  }
  __syncthreads();
  float h[16];
  #pragma unroll
  for (int s = 0; s < 16; ++s) h[s] = 0.f;
  float sdt = 0.f;
  const float* dtp = dt + (size_t)(b * LL + t0) * DI + d;
  const float* xp  = xc + (size_t)(b * LL + t0) * DI + d;
  float dtc = dtp[0], xv = xp[0];
  for (int j = 0; j < LC; ++j) {
    float dtn = 0.f, xn = 0.f;
    if (j + 1 < LC) { dtn = dtp[(size_t)(j + 1) * DI]; xn = xp[(size_t)(j + 1) * DI]; }
    float u = dtc * xv;
    sdt += dtc;
    #pragma unroll
    for (int s = 0; s < 16; ++s) {
      float dA = __expf(dtc * As[s]);
      h[s] = h[s] * dA + u * Bs[j][s];
    }
    dtc = dtn; xv = xn;
  }
  size_t base = (size_t)(b * G_CHUNK + g) * DI + d;
  #pragma unroll
  for (int s4 = 0; s4 < 4; ++s4) {
    float4 o = make_float4(h[s4 * 4], h[s4 * 4 + 1], h[s4 * 4 + 2], h[s4 * 4 + 3]);
    *(float4*)&hend[base * 16 + s4 * 4] = o;
  }
  sdt_out[base] = sdt;
}

// Combine: serial scan over chunk states per (b,d,s). h0[g] = incoming state.
__global__ __launch_bounds__(256) void scan_combine(const float* __restrict__ hend,
    const float* __restrict__ sdt, const float* __restrict__ A_log,
    float* __restrict__ h0) {
  int idx = blockIdx.x * 256 + threadIdx.x;   // 16384 lanes total
  int b = idx / (DI * DS);
  int r = idx % (DI * DS);
  int d = r >> 4, s = r & 15;
  float As = -__expf(A_log[d * DS + s]);
  float hc = 0.f;
  for (int g = 0; g < G_CHUNK; ++g) {
    size_t base = (size_t)(b * G_CHUNK + g) * DI + d;
    h0[base * 16 + s] = hc;
    hc = hc * __expf(As * sdt[base]) + hend[base * 16 + s];
  }
}

// Pass B: re-scan each chunk from true h0; emit gated y.
__global__ __launch_bounds__(512) void scan_passB(const float* __restrict__ dt,
    const float* __restrict__ xc, const float* __restrict__ xz,
    const float* __restrict__ proj, const float* __restrict__ A_log,
    const float* __restrict__ Dv, const float* __restrict__ h0,
    float* __restrict__ y) {
  int g = blockIdx.x, b = blockIdx.y;
  int d = threadIdx.x;
  int t0 = g * LC;
  __shared__ float Bs[LC][16], Cs[LC][16];
  int tid = threadIdx.x;
  if (tid < LC * 4) {
    int row = tid >> 2, q = (tid & 3) * 4;
    *(float4*)&Bs[row][q] =
        *(const float4*)&proj[(size_t)(b * LL + t0 + row) * NPROJ + DTR + q];
  } else if (tid < LC * 8) {
    int t2 = tid - LC * 4;
    int row = t2 >> 2, q = (t2 & 3) * 4;
    *(float4*)&Cs[row][q] =
        *(const float4*)&proj[(size_t)(b * LL + t0 + row) * NPROJ + DTR + DS + q];
  }
  float As[16];
  #pragma unroll
  for (int s4 = 0; s4 < 4; ++s4) {
    float4 a4 = *(const float4*)&A_log[d * DS + s4 * 4];
    As[s4 * 4 + 0] = -__expf(a4.x);
    As[s4 * 4 + 1] = -__expf(a4.y);
    As[s4 * 4 + 2] = -__expf(a4.z);
    As[s4 * 4 + 3] = -__expf(a4.w);
  }
  float h[16];
  size_t base = (size_t)(b * G_CHUNK + g) * DI + d;
  #pragma unroll
  for (int s4 = 0; s4 < 4; ++s4) {
    float4 h4 = *(const float4*)&h0[base * 16 + s4 * 4];
    h[s4 * 4 + 0] = h4.x; h[s4 * 4 + 1] = h4.y;
    h[s4 * 4 + 2] = h4.z; h[s4 * 4 + 3] = h4.w;
  }
  float Dd = Dv[d];
  __syncthreads();
  const float* dtp = dt + (size_t)(b * LL + t0) * DI + d;
  const float* xp  = xc + (size_t)(b * LL + t0) * DI + d;
  const float* zp  = xz + (size_t)(b * LL + t0) * 1024 + DI + d;
  float* yp = y + (size_t)(b * LL + t0) * DI + d;
  float dtc = dtp[0], xv = xp[0], zv = zp[0];
  for (int j = 0; j < LC; ++j) {
    float dtn = 0.f, xn = 0.f, zn = 0.f;
    if (j + 1 < LC) {
      dtn = dtp[(size_t)(j + 1) * DI];
      xn  = xp[(size_t)(j + 1) * DI];
      zn  = zp[(size_t)(j + 1) * 1024];
    }
    float u = dtc * xv;
    float yacc = 0.f;
    #pragma unroll
    for (int s = 0; s < 16; ++s) {
      float dA = __expf(dtc * As[s]);
      h[s] = h[s] * dA + u * Bs[j][s];
      yacc += h[s] * Cs[j][s];
    }
    float yv = yacc + xv * Dd;
    float sig = 1.f / (1.f + __expf(-zv));
    yp[(size_t)j * DI] = yv * zv * sig;
    dtc = dtn; xv = xn; zv = zn;
  }
}

// ------------- LN2 + residual, (B,L,C) -> out (B,C,L) -------------
__global__ __launch_bounds__(256) void ln2_res_kernel(const float* __restrict__ mo,
    const float* __restrict__ x, const float* __restrict__ w, const float* __restrict__ bias,
    float* __restrict__ out) {
  int blk = blockIdx.x;
  int b = blk / (LL / 16);
  int l0 = (blk % (LL / 16)) * 16;
  int tid = threadIdx.x;
  __shared__ float tile[16][CC + 1];
  __shared__ float rs[16][17], rs2[16][17];
  __shared__ float mu[16], rstd[16];
  int ci2 = tid & 15, li2 = tid >> 4;
  const float* mb = mo + (size_t)(b * LL + l0) * CC;
  #pragma unroll
  for (int c0 = 0; c0 < CC; c0 += 16)
    tile[li2][c0 + ci2] = mb[(size_t)li2 * CC + c0 + ci2];
  __syncthreads();
  int li = tid & 15, ci = tid >> 4;
  float s = 0.f, s2 = 0.f;
  #pragma unroll
  for (int j = 0; j < 16; ++j) {
    float v = tile[li][ci * 16 + j];
    s += v; s2 += v * v;
  }
  rs[li][ci] = s; rs2[li][ci] = s2;
  __syncthreads();
  if (ci == 0) {
    float a = 0.f, a2 = 0.f;
    #pragma unroll
    for (int j = 0; j < 16; ++j) { a += rs[li][j]; a2 += rs2[li][j]; }
    float m = a * (1.f / CC);
    float var = a2 * (1.f / CC) - m * m;
    mu[li] = m; rstd[li] = rsqrtf(var + 1e-5f);
  }
  __syncthreads();
  int wli = tid & 15, wci = tid >> 4;
  const float* xb = x + (size_t)b * CC * LL;
  float* ob = out + (size_t)b * CC * LL;
  #pragma unroll
  for (int c0 = 0; c0 < CC; c0 += 16) {
    int c = c0 + wci;
    size_t idx = (size_t)c * LL + l0 + wli;
    float v = tile[wli][c];
    ob[idx] = xb[idx] + (v - mu[wli]) * rstd[wli] * w[c] + bias[c];
  }
}

extern "C" void kernel_launch(void* const* d_in, const int* in_sizes, int n_in,
                              void* d_out, int out_size, void* d_ws, size_t ws_size,
                              hipStream_t stream) {
  const float* x         = (const float*)d_in[0];
  const float* ln1_w     = (const float*)d_in[1];
  const float* ln1_b     = (const float*)d_in[2];
  const float* ln2_w     = (const float*)d_in[3];
  const float* ln2_b     = (const float*)d_in[4];
  const float* in_proj_w = (const float*)d_in[5];
  const float* conv_w    = (const float*)d_in[6];
  const float* conv_b    = (const float*)d_in[7];
  const float* x_proj_w  = (const float*)d_in[8];
  const float* dt_proj_w = (const float*)d_in[9];
  const float* dt_proj_b = (const float*)d_in[10];
  const float* A_log     = (const float*)d_in[11];
  const float* Dv        = (const float*)d_in[12];
  const float* out_proj_w= (const float*)d_in[13];

  float* ws   = (float*)d_ws;
  float* h    = ws;                          // NL*256
  float* xz   = h + (size_t)NL * CC;         // NL*1024 (xm | z)
  float* xc   = xz + (size_t)NL * 1024;      // NL*512
  float* proj = xc + (size_t)NL * DI;        // NL*48
  float* dtb  = proj + (size_t)NL * NPROJ;   // NL*512
  float* y    = dtb + (size_t)NL * DI;       // NL*512
  float* xpwt = y + (size_t)NL * DI;         // 512*48
  float* hend = xpwt + (size_t)DI * NPROJ;   // BB*G*DI*16
  float* h0   = hend + (size_t)BB * G_CHUNK * DI * 16;  // BB*G*DI*16
  float* sdt  = h0 + (size_t)BB * G_CHUNK * DI * 16;    // BB*G*DI
  float* mo   = h;                           // reuse h (dead after gemm1)

  ln1_kernel<<<NL / 16, 256, 0, stream>>>(x, ln1_w, ln1_b, h);
  gemm_nt<<<dim3(1024 / 64, NL / 64), 256, 0, stream>>>(h, in_proj_w, xz, NL, 1024, 256);
  conv_silu_kernel<<<NL, 512, 0, stream>>>(xz, conv_w, conv_b, xc);
  transpose_xpw<<<(NPROJ * DI + 255) / 256, 256, 0, stream>>>(x_proj_w, xpwt);
  xproj_kernel<<<NL / 16, 256, 0, stream>>>(xc, xpwt, proj);
  dt_kernel<<<NL, 512, 0, stream>>>(proj, dt_proj_w, dt_proj_b, dtb);
  scan_passA<<<dim3(G_CHUNK, BB), 512, 0, stream>>>(dtb, xc, proj, A_log, hend, sdt);
  scan_combine<<<BB * DI * DS / 256, 256, 0, stream>>>(hend, sdt, A_log, h0);
  scan_passB<<<dim3(G_CHUNK, BB), 512, 0, stream>>>(dtb, xc, xz, proj, A_log, Dv, h0, y);
  gemm_nt<<<dim3(256 / 64, NL / 64), 256, 0, stream>>>(y, out_proj_w, mo, NL, 256, 512);
  ln2_res_kernel<<<NL / 16, 256, 0, stream>>>(mo, x, ln2_w, ln2_b, (float*)d_out);
}

// Round 4
// 277.094 us; speedup vs baseline: 4.9312x; 1.1996x over previous
//
#include <hip/hip_runtime.h>
#include <hip/hip_bf16.h>
#include <math.h>

#define BB 2
#define CC 256
#define LL 4096
#define NL (BB*LL)
#define DI 512
#define DTR 16
#define DS 16
#define NPROJ 48
#define G_CHUNK 128
#define LC (LL / G_CHUNK)   // 32 steps per chunk

typedef __attribute__((ext_vector_type(8))) short bf16x8;
typedef __attribute__((ext_vector_type(4))) float f32x4;

// ---------------- LN1: x (B,C,L) -> h (B,L,C) bf16, normalized over C ----------------
__global__ __launch_bounds__(256) void ln1_kernel(const float* __restrict__ x,
    const float* __restrict__ w, const float* __restrict__ bias, __hip_bfloat16* __restrict__ h) {
  int blk = blockIdx.x;
  int b = blk / (LL / 16);
  int l0 = (blk % (LL / 16)) * 16;
  int tid = threadIdx.x;
  int li = tid & 15, ci = tid >> 4;
  __shared__ float tile[CC][17];
  __shared__ float rs[16][17], rs2[16][17];
  __shared__ float mu[16], rstd[16];
  const float* xb = x + (size_t)b * CC * LL;
  #pragma unroll
  for (int c0 = 0; c0 < CC; c0 += 16)
    tile[c0 + ci][li] = xb[(size_t)(c0 + ci) * LL + l0 + li];
  __syncthreads();
  float s = 0.f, s2 = 0.f;
  #pragma unroll
  for (int j = 0; j < 16; ++j) {
    float v = tile[ci * 16 + j][li];
    s += v; s2 += v * v;
  }
  rs[li][ci] = s; rs2[li][ci] = s2;
  __syncthreads();
  if (ci == 0) {
    float a = 0.f, a2 = 0.f;
    #pragma unroll
    for (int j = 0; j < 16; ++j) { a += rs[li][j]; a2 += rs2[li][j]; }
    float m = a * (1.f / CC);
    float var = a2 * (1.f / CC) - m * m;
    mu[li] = m; rstd[li] = rsqrtf(var + 1e-5f);
  }
  __syncthreads();
  int ci2 = tid & 15, li2 = tid >> 4;
  __hip_bfloat16* hb = h + (size_t)(b * LL + l0) * CC;
  #pragma unroll
  for (int c0 = 0; c0 < CC; c0 += 16) {
    int c = c0 + ci2;
    float v = tile[c][li2];
    hb[(size_t)li2 * CC + c] = __float2bfloat16((v - mu[li2]) * rstd[li2] * w[c] + bias[c]);
  }
}

// -------- convert fp32 weights -> bf16 (in_proj_w then out_proj_w) --------
// total elements = 1024*256 + 256*512 = 393216 -> launch 1536 blocks of 256.
__global__ void convert_w(const float* __restrict__ w1, const float* __restrict__ w2,
    __hip_bfloat16* __restrict__ w1b, __hip_bfloat16* __restrict__ w2b) {
  int i = blockIdx.x * 256 + threadIdx.x;
  if (i < 1024 * 256) {
    w1b[i] = __float2bfloat16(w1[i]);
  } else {
    int j = i - 1024 * 256;
    if (j < 256 * 512) w2b[j] = __float2bfloat16(w2[j]);
  }
}

// ======== bf16 MFMA GEMM: C[M,N](f32) = A[M,K](bf16) @ W[N,K](bf16)^T ========
// BM x BN tile, BK=32, 256 threads = 4 waves in 2x2. Wave tile (BM/2)x(BN/2).
template<int BM, int BN>
__global__ __launch_bounds__(256) void gemm_bf16(const short* __restrict__ A,
    const short* __restrict__ Bw, float* __restrict__ C, int M, int N, int K) {
  constexpr int TI = BM / 32, TJ = BN / 32;
  __shared__ short As[BM][40];   // 32 + 8 pad: <=2-way bank aliasing (free)
  __shared__ short Bs[BN][40];
  int m0 = blockIdx.y * BM, n0 = blockIdx.x * BN;
  int tid = threadIdx.x;
  int wid = tid >> 6, lane = tid & 63;
  int quad = lane >> 4, l16 = lane & 15;
  int wm = (wid >> 1) * (BM / 2), wn = (wid & 1) * (BN / 2);
  f32x4 acc[TI][TJ];
  #pragma unroll
  for (int i = 0; i < TI; ++i)
    #pragma unroll
    for (int j = 0; j < TJ; ++j)
      #pragma unroll
      for (int r = 0; r < 4; ++r) acc[i][j][r] = 0.f;
  for (int k0 = 0; k0 < K; k0 += 32) {
    #pragma unroll
    for (int c = tid; c < BM * 4; c += 256) {
      int row = c >> 2, pos = c & 3;
      *(bf16x8*)&As[row][pos * 8] = *(const bf16x8*)&A[(size_t)(m0 + row) * K + k0 + pos * 8];
    }
    #pragma unroll
    for (int c = tid; c < BN * 4; c += 256) {
      int row = c >> 2, pos = c & 3;
      *(bf16x8*)&Bs[row][pos * 8] = *(const bf16x8*)&Bw[(size_t)(n0 + row) * K + k0 + pos * 8];
    }
    __syncthreads();
    bf16x8 af[TI], bfr[TJ];
    #pragma unroll
    for (int i = 0; i < TI; ++i)
      af[i] = *(const bf16x8*)&As[wm + i * 16 + l16][quad * 8];
    #pragma unroll
    for (int j = 0; j < TJ; ++j)
      bfr[j] = *(const bf16x8*)&Bs[wn + j * 16 + l16][quad * 8];
    #pragma unroll
    for (int i = 0; i < TI; ++i)
      #pragma unroll
      for (int j = 0; j < TJ; ++j)
        acc[i][j] = __builtin_amdgcn_mfma_f32_16x16x32_bf16(af[i], bfr[j], acc[i][j], 0, 0, 0);
    __syncthreads();
  }
  #pragma unroll
  for (int i = 0; i < TI; ++i)
    #pragma unroll
    for (int j = 0; j < TJ; ++j) {
      int rbase = m0 + wm + i * 16 + quad * 4;
      int col = n0 + wn + j * 16 + l16;
      #pragma unroll
      for (int r = 0; r < 4; ++r)
        C[(size_t)(rbase + r) * N + col] = acc[i][j][r];
    }
}

// ------------- depthwise causal conv (k=4) + bias + SiLU -------------
__global__ __launch_bounds__(512) void conv_silu_kernel(const float* __restrict__ xz,
    const float* __restrict__ cw, const float* __restrict__ cb, float* __restrict__ xc) {
  int blk = blockIdx.x;            // b*LL + l
  int b = blk / LL, l = blk % LL;
  int d = threadIdx.x;             // 512
  const float4 w4 = *(const float4*)&cw[d * 4];
  const float* base = xz + (size_t)b * LL * 1024 + d;
  float s = cb[d];
  if (l >= 3) s += base[(size_t)(l - 3) * 1024] * w4.x;
  if (l >= 2) s += base[(size_t)(l - 2) * 1024] * w4.y;
  if (l >= 1) s += base[(size_t)(l - 1) * 1024] * w4.z;
  s += base[(size_t)l * 1024] * w4.w;
  xc[(size_t)blk * DI + d] = s / (1.f + __expf(-s));
}

// ------------- transpose x_proj_w (48,512) -> (512,48) -------------
__global__ void transpose_xpw(const float* __restrict__ src, float* __restrict__ dst) {
  int idx = blockIdx.x * 256 + threadIdx.x;
  if (idx < NPROJ * DI) {
    int j = idx / DI, k = idx % DI;
    dst[k * NPROJ + j] = src[idx];
  }
}

// ------------- x_proj: proj (NL,48) = xc (NL,512) @ Wt (512,48) -------------
__global__ __launch_bounds__(256) void xproj_kernel(const float* __restrict__ xc,
    const float* __restrict__ wt, float* __restrict__ proj) {
  int r0 = blockIdx.x * 16;
  int tid = threadIdx.x;
  __shared__ float xs[16][DI];
  for (int i = tid; i < 16 * (DI / 4); i += 256) {
    int row = i / (DI / 4);
    int c4 = (i % (DI / 4)) * 4;
    *(float4*)&xs[row][c4] = *(const float4*)&xc[(size_t)(r0 + row) * DI + c4];
  }
  __syncthreads();
  for (int o = tid; o < 16 * NPROJ; o += 256) {
    int row = o / NPROJ, j = o % NPROJ;
    float acc = 0.f;
    for (int k = 0; k < DI; ++k)
      acc += xs[row][k] * wt[k * NPROJ + j];
    proj[(size_t)(r0 + row) * NPROJ + j] = acc;
  }
}

// ------------- dt = softplus(proj[:, :16] @ dtw^T + dtb) -------------
__global__ __launch_bounds__(512) void dt_kernel(const float* __restrict__ proj,
    const float* __restrict__ dtw, const float* __restrict__ dtbias, float* __restrict__ dt) {
  int row = blockIdx.x;
  int d = threadIdx.x;
  __shared__ float pr[DTR];
  if (d < DTR) pr[d] = proj[(size_t)row * NPROJ + d];
  __syncthreads();
  float acc = dtbias[d];
  const float4* wr = (const float4*)&dtw[d * DTR];
  #pragma unroll
  for (int r4 = 0; r4 < 4; ++r4) {
    float4 w4 = wr[r4];
    acc += pr[r4 * 4 + 0] * w4.x + pr[r4 * 4 + 1] * w4.y
         + pr[r4 * 4 + 2] * w4.z + pr[r4 * 4 + 3] * w4.w;
  }
  float sp = (acc > 20.f) ? acc : log1pf(__expf(acc));
  dt[(size_t)row * DI + d] = sp;
}

// ===================== chunk-parallel selective scan =====================
__global__ __launch_bounds__(512) void scan_passA(const float* __restrict__ dt,
    const float* __restrict__ xc, const float* __restrict__ proj,
    const float* __restrict__ A_log, float* __restrict__ hend,
    float* __restrict__ sdt_out) {
  int g = blockIdx.x, b = blockIdx.y;
  int d = threadIdx.x;
  int t0 = g * LC;
  __shared__ float Bs[LC][16];
  int tid = threadIdx.x;
  if (tid < LC * 4) {
    int row = tid >> 2, q = (tid & 3) * 4;
    *(float4*)&Bs[row][q] =
        *(const float4*)&proj[(size_t)(b * LL + t0 + row) * NPROJ + DTR + q];
  }
  float As[16];
  #pragma unroll
  for (int s4 = 0; s4 < 4; ++s4) {
    float4 a4 = *(const float4*)&A_log[d * DS + s4 * 4];
    As[s4 * 4 + 0] = -__expf(a4.x);
    As[s4 * 4 + 1] = -__expf(a4.y);
    As[s4 * 4 + 2] = -__expf(a4.z);
    As[s4 * 4 + 3] = -__expf(a4.w);
  }
  __syncthreads();
  float h[16];
  #pragma unroll
  for (int s = 0; s < 16; ++s) h[s] = 0.f;
  float sdt = 0.f;
  const float* dtp = dt + (size_t)(b * LL + t0) * DI + d;
  const float* xp  = xc + (size_t)(b * LL + t0) * DI + d;
  float dtc = dtp[0], xv = xp[0];
  for (int j = 0; j < LC; ++j) {
    float dtn = 0.f, xn = 0.f;
    if (j + 1 < LC) { dtn = dtp[(size_t)(j + 1) * DI]; xn = xp[(size_t)(j + 1) * DI]; }
    float u = dtc * xv;
    sdt += dtc;
    #pragma unroll
    for (int s = 0; s < 16; ++s) {
      float dA = __expf(dtc * As[s]);
      h[s] = h[s] * dA + u * Bs[j][s];
    }
    dtc = dtn; xv = xn;
  }
  size_t base = (size_t)(b * G_CHUNK + g) * DI + d;
  #pragma unroll
  for (int s4 = 0; s4 < 4; ++s4) {
    float4 o = make_float4(h[s4 * 4], h[s4 * 4 + 1], h[s4 * 4 + 2], h[s4 * 4 + 3]);
    *(float4*)&hend[base * 16 + s4 * 4] = o;
  }
  sdt_out[base] = sdt;
}

__global__ __launch_bounds__(256) void scan_combine(const float* __restrict__ hend,
    const float* __restrict__ sdt, const float* __restrict__ A_log,
    float* __restrict__ h0) {
  int idx = blockIdx.x * 256 + threadIdx.x;   // 16384 lanes total
  int b = idx / (DI * DS);
  int r = idx % (DI * DS);
  int d = r >> 4, s = r & 15;
  float As = -__expf(A_log[d * DS + s]);
  float hc = 0.f;
  for (int g = 0; g < G_CHUNK; ++g) {
    size_t base = (size_t)(b * G_CHUNK + g) * DI + d;
    h0[base * 16 + s] = hc;
    hc = hc * __expf(As * sdt[base]) + hend[base * 16 + s];
  }
}

__global__ __launch_bounds__(512) void scan_passB(const float* __restrict__ dt,
    const float* __restrict__ xc, const float* __restrict__ xz,
    const float* __restrict__ proj, const float* __restrict__ A_log,
    const float* __restrict__ Dv, const float* __restrict__ h0,
    __hip_bfloat16* __restrict__ y) {
  int g = blockIdx.x, b = blockIdx.y;
  int d = threadIdx.x;
  int t0 = g * LC;
  __shared__ float Bs[LC][16], Cs[LC][16];
  int tid = threadIdx.x;
  if (tid < LC * 4) {
    int row = tid >> 2, q = (tid & 3) * 4;
    *(float4*)&Bs[row][q] =
        *(const float4*)&proj[(size_t)(b * LL + t0 + row) * NPROJ + DTR + q];
  } else if (tid < LC * 8) {
    int t2 = tid - LC * 4;
    int row = t2 >> 2, q = (t2 & 3) * 4;
    *(float4*)&Cs[row][q] =
        *(const float4*)&proj[(size_t)(b * LL + t0 + row) * NPROJ + DTR + DS + q];
  }
  float As[16];
  #pragma unroll
  for (int s4 = 0; s4 < 4; ++s4) {
    float4 a4 = *(const float4*)&A_log[d * DS + s4 * 4];
    As[s4 * 4 + 0] = -__expf(a4.x);
    As[s4 * 4 + 1] = -__expf(a4.y);
    As[s4 * 4 + 2] = -__expf(a4.z);
    As[s4 * 4 + 3] = -__expf(a4.w);
  }
  float h[16];
  size_t base = (size_t)(b * G_CHUNK + g) * DI + d;
  #pragma unroll
  for (int s4 = 0; s4 < 4; ++s4) {
    float4 h4 = *(const float4*)&h0[base * 16 + s4 * 4];
    h[s4 * 4 + 0] = h4.x; h[s4 * 4 + 1] = h4.y;
    h[s4 * 4 + 2] = h4.z; h[s4 * 4 + 3] = h4.w;
  }
  float Dd = Dv[d];
  __syncthreads();
  const float* dtp = dt + (size_t)(b * LL + t0) * DI + d;
  const float* xp  = xc + (size_t)(b * LL + t0) * DI + d;
  const float* zp  = xz + (size_t)(b * LL + t0) * 1024 + DI + d;
  __hip_bfloat16* yp = y + (size_t)(b * LL + t0) * DI + d;
  float dtc = dtp[0], xv = xp[0], zv = zp[0];
  for (int j = 0; j < LC; ++j) {
    float dtn = 0.f, xn = 0.f, zn = 0.f;
    if (j + 1 < LC) {
      dtn = dtp[(size_t)(j + 1) * DI];
      xn  = xp[(size_t)(j + 1) * DI];
      zn  = zp[(size_t)(j + 1) * 1024];
    }
    float u = dtc * xv;
    float yacc = 0.f;
    #pragma unroll
    for (int s = 0; s < 16; ++s) {
      float dA = __expf(dtc * As[s]);
      h[s] = h[s] * dA + u * Bs[j][s];
      yacc += h[s] * Cs[j][s];
    }
    float yv = yacc + xv * Dd;
    float sig = 1.f / (1.f + __expf(-zv));
    yp[(size_t)j * DI] = __float2bfloat16(yv * zv * sig);
    dtc = dtn; xv = xn; zv = zn;
  }
}

// ------------- LN2 + residual, (B,L,C) -> out (B,C,L) -------------
__global__ __launch_bounds__(256) void ln2_res_kernel(const float* __restrict__ mo,
    const float* __restrict__ x, const float* __restrict__ w, const float* __restrict__ bias,
    float* __restrict__ out) {
  int blk = blockIdx.x;
  int b = blk / (LL / 16);
  int l0 = (blk % (LL / 16)) * 16;
  int tid = threadIdx.x;
  __shared__ float tile[16][CC + 1];
  __shared__ float rs[16][17], rs2[16][17];
  __shared__ float mu[16], rstd[16];
  int ci2 = tid & 15, li2 = tid >> 4;
  const float* mb = mo + (size_t)(b * LL + l0) * CC;
  #pragma unroll
  for (int c0 = 0; c0 < CC; c0 += 16)
    tile[li2][c0 + ci2] = mb[(size_t)li2 * CC + c0 + ci2];
  __syncthreads();
  int li = tid & 15, ci = tid >> 4;
  float s = 0.f, s2 = 0.f;
  #pragma unroll
  for (int j = 0; j < 16; ++j) {
    float v = tile[li][ci * 16 + j];
    s += v; s2 += v * v;
  }
  rs[li][ci] = s; rs2[li][ci] = s2;
  __syncthreads();
  if (ci == 0) {
    float a = 0.f, a2 = 0.f;
    #pragma unroll
    for (int j = 0; j < 16; ++j) { a += rs[li][j]; a2 += rs2[li][j]; }
    float m = a * (1.f / CC);
    float var = a2 * (1.f / CC) - m * m;
    mu[li] = m; rstd[li] = rsqrtf(var + 1e-5f);
  }
  __syncthreads();
  int wli = tid & 15, wci = tid >> 4;
  const float* xb = x + (size_t)b * CC * LL;
  float* ob = out + (size_t)b * CC * LL;
  #pragma unroll
  for (int c0 = 0; c0 < CC; c0 += 16) {
    int c = c0 + wci;
    size_t idx = (size_t)c * LL + l0 + wli;
    float v = tile[wli][c];
    ob[idx] = xb[idx] + (v - mu[wli]) * rstd[wli] * w[c] + bias[c];
  }
}

extern "C" void kernel_launch(void* const* d_in, const int* in_sizes, int n_in,
                              void* d_out, int out_size, void* d_ws, size_t ws_size,
                              hipStream_t stream) {
  const float* x         = (const float*)d_in[0];
  const float* ln1_w     = (const float*)d_in[1];
  const float* ln1_b     = (const float*)d_in[2];
  const float* ln2_w     = (const float*)d_in[3];
  const float* ln2_b     = (const float*)d_in[4];
  const float* in_proj_w = (const float*)d_in[5];
  const float* conv_w    = (const float*)d_in[6];
  const float* conv_b    = (const float*)d_in[7];
  const float* x_proj_w  = (const float*)d_in[8];
  const float* dt_proj_w = (const float*)d_in[9];
  const float* dt_proj_b = (const float*)d_in[10];
  const float* A_log     = (const float*)d_in[11];
  const float* Dv        = (const float*)d_in[12];
  const float* out_proj_w= (const float*)d_in[13];

  char* wsp = (char*)d_ws;
  size_t off = 0;
  auto alloc = [&](size_t bytes) -> void* {
    void* p = wsp + off;
    off += (bytes + 255) & ~(size_t)255;
    return p;
  };
  float* xz   = (float*)alloc((size_t)NL * 1024 * 4);
  float* xc   = (float*)alloc((size_t)NL * DI * 4);
  float* proj = (float*)alloc((size_t)NL * NPROJ * 4);
  float* dtb  = (float*)alloc((size_t)NL * DI * 4);
  float* hend = (float*)alloc((size_t)BB * G_CHUNK * DI * 16 * 4);
  float* h0   = (float*)alloc((size_t)BB * G_CHUNK * DI * 16 * 4);
  float* sdt  = (float*)alloc((size_t)BB * G_CHUNK * DI * 4);
  float* mo   = (float*)alloc((size_t)NL * CC * 4);
  float* xpwt = (float*)alloc((size_t)DI * NPROJ * 4);
  __hip_bfloat16* hbf = (__hip_bfloat16*)alloc((size_t)NL * CC * 2);
  __hip_bfloat16* ybf = (__hip_bfloat16*)alloc((size_t)NL * DI * 2);
  __hip_bfloat16* w1b = (__hip_bfloat16*)alloc((size_t)1024 * 256 * 2);
  __hip_bfloat16* w2b = (__hip_bfloat16*)alloc((size_t)256 * 512 * 2);

  ln1_kernel<<<NL / 16, 256, 0, stream>>>(x, ln1_w, ln1_b, hbf);
  convert_w<<<(1024 * 256 + 256 * 512 + 255) / 256, 256, 0, stream>>>(in_proj_w, out_proj_w, w1b, w2b);
  gemm_bf16<128, 128><<<dim3(1024 / 128, NL / 128), 256, 0, stream>>>(
      (const short*)hbf, (const short*)w1b, xz, NL, 1024, 256);
  conv_silu_kernel<<<NL, 512, 0, stream>>>(xz, conv_w, conv_b, xc);
  transpose_xpw<<<(NPROJ * DI + 255) / 256, 256, 0, stream>>>(x_proj_w, xpwt);
  xproj_kernel<<<NL / 16, 256, 0, stream>>>(xc, xpwt, proj);
  dt_kernel<<<NL, 512, 0, stream>>>(proj, dt_proj_w, dt_proj_b, dtb);
  scan_passA<<<dim3(G_CHUNK, BB), 512, 0, stream>>>(dtb, xc, proj, A_log, hend, sdt);
  scan_combine<<<BB * DI * DS / 256, 256, 0, stream>>>(hend, sdt, A_log, h0);
  scan_passB<<<dim3(G_CHUNK, BB), 512, 0, stream>>>(dtb, xc, xz, proj, A_log, Dv, h0, ybf);
  gemm_bf16<128, 64><<<dim3(256 / 64, NL / 128), 256, 0, stream>>>(
      (const short*)ybf, (const short*)w2b, mo, NL, 256, 512);
  ln2_res_kernel<<<NL / 16, 256, 0, stream>>>(mo, x, ln2_w, ln2_b, (float*)d_out);
}

// Round 5
// 236.694 us; speedup vs baseline: 5.7728x; 1.1707x over previous
//
#include <hip/hip_runtime.h>
#include <hip/hip_bf16.h>
#include <math.h>

#define BB 2
#define CC 256
#define LL 4096
#define NL (BB*LL)
#define DI 512
#define DTR 16
#define DS 16
#define NPROJ 48
#define G_CHUNK 128
#define LC (LL / G_CHUNK)   // 32 steps per chunk

typedef __attribute__((ext_vector_type(8))) short bf16x8;
typedef __attribute__((ext_vector_type(4))) float f32x4;

// ---------------- LN1: x (B,C,L) -> h (B,L,C) bf16, normalized over C ----------------
__global__ __launch_bounds__(256) void ln1_kernel(const float* __restrict__ x,
    const float* __restrict__ w, const float* __restrict__ bias, __hip_bfloat16* __restrict__ h) {
  int blk = blockIdx.x;
  int b = blk / (LL / 16);
  int l0 = (blk % (LL / 16)) * 16;
  int tid = threadIdx.x;
  int li = tid & 15, ci = tid >> 4;
  __shared__ float tile[CC][17];
  __shared__ float rs[16][17], rs2[16][17];
  __shared__ float mu[16], rstd[16];
  const float* xb = x + (size_t)b * CC * LL;
  #pragma unroll
  for (int c0 = 0; c0 < CC; c0 += 16)
    tile[c0 + ci][li] = xb[(size_t)(c0 + ci) * LL + l0 + li];
  __syncthreads();
  float s = 0.f, s2 = 0.f;
  #pragma unroll
  for (int j = 0; j < 16; ++j) {
    float v = tile[ci * 16 + j][li];
    s += v; s2 += v * v;
  }
  rs[li][ci] = s; rs2[li][ci] = s2;
  __syncthreads();
  if (ci == 0) {
    float a = 0.f, a2 = 0.f;
    #pragma unroll
    for (int j = 0; j < 16; ++j) { a += rs[li][j]; a2 += rs2[li][j]; }
    float m = a * (1.f / CC);
    float var = a2 * (1.f / CC) - m * m;
    mu[li] = m; rstd[li] = rsqrtf(var + 1e-5f);
  }
  __syncthreads();
  int ci2 = tid & 15, li2 = tid >> 4;
  __hip_bfloat16* hb = h + (size_t)(b * LL + l0) * CC;
  #pragma unroll
  for (int c0 = 0; c0 < CC; c0 += 16) {
    int c = c0 + ci2;
    float v = tile[c][li2];
    hb[(size_t)li2 * CC + c] = __float2bfloat16((v - mu[li2]) * rstd[li2] * w[c] + bias[c]);
  }
}

// -------- convert fp32 weights -> bf16 (in_proj_w, out_proj_w, x_proj_w) --------
// elements: 262144 + 131072 + 24576 = 417792 -> 1632 blocks of 256
__global__ void convert_w(const float* __restrict__ w1, const float* __restrict__ w2,
    const float* __restrict__ w3, __hip_bfloat16* __restrict__ w1b,
    __hip_bfloat16* __restrict__ w2b, __hip_bfloat16* __restrict__ w3b) {
  int i = blockIdx.x * 256 + threadIdx.x;
  if (i < 1024 * 256) {
    w1b[i] = __float2bfloat16(w1[i]);
  } else if (i < 1024 * 256 + 256 * 512) {
    int j = i - 1024 * 256;
    w2b[j] = __float2bfloat16(w2[j]);
  } else {
    int j = i - (1024 * 256 + 256 * 512);
    if (j < NPROJ * DI) w3b[j] = __float2bfloat16(w3[j]);
  }
}

// ======== bf16 MFMA GEMM: C[M,N](f32) = A[M,K](bf16) @ W[N,K](bf16)^T ========
// BM x BN tile, BK=32, 256 threads = 4 waves in 2x2. Wave tile (BM/2)x(BN/2).
template<int BM, int BN>
__global__ __launch_bounds__(256) void gemm_bf16(const short* __restrict__ A,
    const short* __restrict__ Bw, float* __restrict__ C, int M, int N, int K) {
  constexpr int TI = BM / 32, TJ = BN / 32;
  __shared__ short As[BM][40];   // 32 + 8 pad: <=2-way bank aliasing (free)
  __shared__ short Bs[BN][40];
  int m0 = blockIdx.y * BM, n0 = blockIdx.x * BN;
  int tid = threadIdx.x;
  int wid = tid >> 6, lane = tid & 63;
  int quad = lane >> 4, l16 = lane & 15;
  int wm = (wid >> 1) * (BM / 2), wn = (wid & 1) * (BN / 2);
  f32x4 acc[TI][TJ];
  #pragma unroll
  for (int i = 0; i < TI; ++i)
    #pragma unroll
    for (int j = 0; j < TJ; ++j)
      #pragma unroll
      for (int r = 0; r < 4; ++r) acc[i][j][r] = 0.f;
  for (int k0 = 0; k0 < K; k0 += 32) {
    #pragma unroll
    for (int c = tid; c < BM * 4; c += 256) {
      int row = c >> 2, pos = c & 3;
      *(bf16x8*)&As[row][pos * 8] = *(const bf16x8*)&A[(size_t)(m0 + row) * K + k0 + pos * 8];
    }
    #pragma unroll
    for (int c = tid; c < BN * 4; c += 256) {
      int row = c >> 2, pos = c & 3;
      *(bf16x8*)&Bs[row][pos * 8] = *(const bf16x8*)&Bw[(size_t)(n0 + row) * K + k0 + pos * 8];
    }
    __syncthreads();
    bf16x8 af[TI], bfr[TJ];
    #pragma unroll
    for (int i = 0; i < TI; ++i)
      af[i] = *(const bf16x8*)&As[wm + i * 16 + l16][quad * 8];
    #pragma unroll
    for (int j = 0; j < TJ; ++j)
      bfr[j] = *(const bf16x8*)&Bs[wn + j * 16 + l16][quad * 8];
    #pragma unroll
    for (int i = 0; i < TI; ++i)
      #pragma unroll
      for (int j = 0; j < TJ; ++j)
        acc[i][j] = __builtin_amdgcn_mfma_f32_16x16x32_bf16(af[i], bfr[j], acc[i][j], 0, 0, 0);
    __syncthreads();
  }
  #pragma unroll
  for (int i = 0; i < TI; ++i)
    #pragma unroll
    for (int j = 0; j < TJ; ++j) {
      int rbase = m0 + wm + i * 16 + quad * 4;
      int col = n0 + wn + j * 16 + l16;
      #pragma unroll
      for (int r = 0; r < 4; ++r)
        C[(size_t)(rbase + r) * N + col] = acc[i][j][r];
    }
}

// ===== xproj MFMA: proj (NL,48) = xcb (NL,512 bf16) @ xpwb (48,512 bf16)^T =====
// 64x64 tile (N=48 zero-padded to 64), grid = NL/64 blocks.
__global__ __launch_bounds__(256) void xproj_mfma(const short* __restrict__ A,
    const short* __restrict__ Bw, float* __restrict__ proj) {
  __shared__ short As[64][40];
  __shared__ short Bs[64][40];
  int m0 = blockIdx.x * 64;
  int tid = threadIdx.x;
  int wid = tid >> 6, lane = tid & 63;
  int quad = lane >> 4, l16 = lane & 15;
  int wm = (wid >> 1) * 32, wn = (wid & 1) * 32;
  f32x4 acc[2][2];
  #pragma unroll
  for (int i = 0; i < 2; ++i)
    #pragma unroll
    for (int j = 0; j < 2; ++j)
      #pragma unroll
      for (int r = 0; r < 4; ++r) acc[i][j][r] = 0.f;
  int row = tid >> 2, pos = tid & 3;   // one 16B chunk per thread per k-step
  for (int k0 = 0; k0 < DI; k0 += 32) {
    *(bf16x8*)&As[row][pos * 8] = *(const bf16x8*)&A[(size_t)(m0 + row) * DI + k0 + pos * 8];
    if (row < NPROJ) {
      *(bf16x8*)&Bs[row][pos * 8] = *(const bf16x8*)&Bw[(size_t)row * DI + k0 + pos * 8];
    } else {
      bf16x8 z = {0, 0, 0, 0, 0, 0, 0, 0};
      *(bf16x8*)&Bs[row][pos * 8] = z;
    }
    __syncthreads();
    bf16x8 af[2], bfr[2];
    #pragma unroll
    for (int i = 0; i < 2; ++i)
      af[i] = *(const bf16x8*)&As[wm + i * 16 + l16][quad * 8];
    #pragma unroll
    for (int j = 0; j < 2; ++j)
      bfr[j] = *(const bf16x8*)&Bs[wn + j * 16 + l16][quad * 8];
    #pragma unroll
    for (int i = 0; i < 2; ++i)
      #pragma unroll
      for (int j = 0; j < 2; ++j)
        acc[i][j] = __builtin_amdgcn_mfma_f32_16x16x32_bf16(af[i], bfr[j], acc[i][j], 0, 0, 0);
    __syncthreads();
  }
  #pragma unroll
  for (int i = 0; i < 2; ++i)
    #pragma unroll
    for (int j = 0; j < 2; ++j) {
      int rbase = m0 + wm + i * 16 + quad * 4;
      int col = wn + j * 16 + l16;
      if (col < NPROJ) {
        #pragma unroll
        for (int r = 0; r < 4; ++r)
          proj[(size_t)(rbase + r) * NPROJ + col] = acc[i][j][r];
      }
    }
}

// ------- depthwise causal conv (k=4) + bias + SiLU; emits fp32 + bf16 -------
__global__ __launch_bounds__(512) void conv_silu_kernel(const float* __restrict__ xz,
    const float* __restrict__ cw, const float* __restrict__ cb,
    float* __restrict__ xc, __hip_bfloat16* __restrict__ xcb) {
  int blk = blockIdx.x;            // b*LL + l
  int b = blk / LL, l = blk % LL;
  int d = threadIdx.x;             // 512
  const float4 w4 = *(const float4*)&cw[d * 4];
  const float* base = xz + (size_t)b * LL * 1024 + d;
  float s = cb[d];
  if (l >= 3) s += base[(size_t)(l - 3) * 1024] * w4.x;
  if (l >= 2) s += base[(size_t)(l - 2) * 1024] * w4.y;
  if (l >= 1) s += base[(size_t)(l - 1) * 1024] * w4.z;
  s += base[(size_t)l * 1024] * w4.w;
  float v = s / (1.f + __expf(-s));
  xc[(size_t)blk * DI + d] = v;
  xcb[(size_t)blk * DI + d] = __float2bfloat16(v);
}

// ------------- dt = softplus(proj[:, :16] @ dtw^T + dtb) -------------
__global__ __launch_bounds__(512) void dt_kernel(const float* __restrict__ proj,
    const float* __restrict__ dtw, const float* __restrict__ dtbias, float* __restrict__ dt) {
  int row = blockIdx.x;
  int d = threadIdx.x;
  __shared__ float pr[DTR];
  if (d < DTR) pr[d] = proj[(size_t)row * NPROJ + d];
  __syncthreads();
  float acc = dtbias[d];
  const float4* wr = (const float4*)&dtw[d * DTR];
  #pragma unroll
  for (int r4 = 0; r4 < 4; ++r4) {
    float4 w4 = wr[r4];
    acc += pr[r4 * 4 + 0] * w4.x + pr[r4 * 4 + 1] * w4.y
         + pr[r4 * 4 + 2] * w4.z + pr[r4 * 4 + 3] * w4.w;
  }
  float sp = (acc > 20.f) ? acc : log1pf(__expf(acc));
  dt[(size_t)row * DI + d] = sp;
}

// ===================== chunk-parallel selective scan =====================
__global__ __launch_bounds__(512) void scan_passA(const float* __restrict__ dt,
    const float* __restrict__ xc, const float* __restrict__ proj,
    const float* __restrict__ A_log, float* __restrict__ hend,
    float* __restrict__ sdt_out) {
  int g = blockIdx.x, b = blockIdx.y;
  int d = threadIdx.x;
  int t0 = g * LC;
  __shared__ float Bs[LC][16];
  int tid = threadIdx.x;
  if (tid < LC * 4) {
    int row = tid >> 2, q = (tid & 3) * 4;
    *(float4*)&Bs[row][q] =
        *(const float4*)&proj[(size_t)(b * LL + t0 + row) * NPROJ + DTR + q];
  }
  float As[16];
  #pragma unroll
  for (int s4 = 0; s4 < 4; ++s4) {
    float4 a4 = *(const float4*)&A_log[d * DS + s4 * 4];
    As[s4 * 4 + 0] = -__expf(a4.x);
    As[s4 * 4 + 1] = -__expf(a4.y);
    As[s4 * 4 + 2] = -__expf(a4.z);
    As[s4 * 4 + 3] = -__expf(a4.w);
  }
  __syncthreads();
  float h[16];
  #pragma unroll
  for (int s = 0; s < 16; ++s) h[s] = 0.f;
  float sdt = 0.f;
  const float* dtp = dt + (size_t)(b * LL + t0) * DI + d;
  const float* xp  = xc + (size_t)(b * LL + t0) * DI + d;
  float dtc = dtp[0], xv = xp[0];
  for (int j = 0; j < LC; ++j) {
    float dtn = 0.f, xn = 0.f;
    if (j + 1 < LC) { dtn = dtp[(size_t)(j + 1) * DI]; xn = xp[(size_t)(j + 1) * DI]; }
    float u = dtc * xv;
    sdt += dtc;
    #pragma unroll
    for (int s = 0; s < 16; ++s) {
      float dA = __expf(dtc * As[s]);
      h[s] = h[s] * dA + u * Bs[j][s];
    }
    dtc = dtn; xv = xn;
  }
  size_t base = (size_t)(b * G_CHUNK + g) * DI + d;
  #pragma unroll
  for (int s4 = 0; s4 < 4; ++s4) {
    float4 o = make_float4(h[s4 * 4], h[s4 * 4 + 1], h[s4 * 4 + 2], h[s4 * 4 + 3]);
    *(float4*)&hend[base * 16 + s4 * 4] = o;
  }
  sdt_out[base] = sdt;
}

__global__ __launch_bounds__(256) void scan_combine(const float* __restrict__ hend,
    const float* __restrict__ sdt, const float* __restrict__ A_log,
    float* __restrict__ h0) {
  int idx = blockIdx.x * 256 + threadIdx.x;   // 16384 lanes total
  int b = idx / (DI * DS);
  int r = idx % (DI * DS);
  int d = r >> 4, s = r & 15;
  float As = -__expf(A_log[d * DS + s]);
  float hc = 0.f;
  for (int g = 0; g < G_CHUNK; ++g) {
    size_t base = (size_t)(b * G_CHUNK + g) * DI + d;
    h0[base * 16 + s] = hc;
    hc = hc * __expf(As * sdt[base]) + hend[base * 16 + s];
  }
}

__global__ __launch_bounds__(512) void scan_passB(const float* __restrict__ dt,
    const float* __restrict__ xc, const float* __restrict__ xz,
    const float* __restrict__ proj, const float* __restrict__ A_log,
    const float* __restrict__ Dv, const float* __restrict__ h0,
    __hip_bfloat16* __restrict__ y) {
  int g = blockIdx.x, b = blockIdx.y;
  int d = threadIdx.x;
  int t0 = g * LC;
  __shared__ float Bs[LC][16], Cs[LC][16];
  int tid = threadIdx.x;
  if (tid < LC * 4) {
    int row = tid >> 2, q = (tid & 3) * 4;
    *(float4*)&Bs[row][q] =
        *(const float4*)&proj[(size_t)(b * LL + t0 + row) * NPROJ + DTR + q];
  } else if (tid < LC * 8) {
    int t2 = tid - LC * 4;
    int row = t2 >> 2, q = (t2 & 3) * 4;
    *(float4*)&Cs[row][q] =
        *(const float4*)&proj[(size_t)(b * LL + t0 + row) * NPROJ + DTR + DS + q];
  }
  float As[16];
  #pragma unroll
  for (int s4 = 0; s4 < 4; ++s4) {
    float4 a4 = *(const float4*)&A_log[d * DS + s4 * 4];
    As[s4 * 4 + 0] = -__expf(a4.x);
    As[s4 * 4 + 1] = -__expf(a4.y);
    As[s4 * 4 + 2] = -__expf(a4.z);
    As[s4 * 4 + 3] = -__expf(a4.w);
  }
  float h[16];
  size_t base = (size_t)(b * G_CHUNK + g) * DI + d;
  #pragma unroll
  for (int s4 = 0; s4 < 4; ++s4) {
    float4 h4 = *(const float4*)&h0[base * 16 + s4 * 4];
    h[s4 * 4 + 0] = h4.x; h[s4 * 4 + 1] = h4.y;
    h[s4 * 4 + 2] = h4.z; h[s4 * 4 + 3] = h4.w;
  }
  float Dd = Dv[d];
  __syncthreads();
  const float* dtp = dt + (size_t)(b * LL + t0) * DI + d;
  const float* xp  = xc + (size_t)(b * LL + t0) * DI + d;
  const float* zp  = xz + (size_t)(b * LL + t0) * 1024 + DI + d;
  __hip_bfloat16* yp = y + (size_t)(b * LL + t0) * DI + d;
  float dtc = dtp[0], xv = xp[0], zv = zp[0];
  for (int j = 0; j < LC; ++j) {
    float dtn = 0.f, xn = 0.f, zn = 0.f;
    if (j + 1 < LC) {
      dtn = dtp[(size_t)(j + 1) * DI];
      xn  = xp[(size_t)(j + 1) * DI];
      zn  = zp[(size_t)(j + 1) * 1024];
    }
    float u = dtc * xv;
    float yacc = 0.f;
    #pragma unroll
    for (int s = 0; s < 16; ++s) {
      float dA = __expf(dtc * As[s]);
      h[s] = h[s] * dA + u * Bs[j][s];
      yacc += h[s] * Cs[j][s];
    }
    float yv = yacc + xv * Dd;
    float sig = 1.f / (1.f + __expf(-zv));
    yp[(size_t)j * DI] = __float2bfloat16(yv * zv * sig);
    dtc = dtn; xv = xn; zv = zn;
  }
}

// ------------- LN2 + residual, (B,L,C) -> out (B,C,L) -------------
__global__ __launch_bounds__(256) void ln2_res_kernel(const float* __restrict__ mo,
    const float* __restrict__ x, const float* __restrict__ w, const float* __restrict__ bias,
    float* __restrict__ out) {
  int blk = blockIdx.x;
  int b = blk / (LL / 16);
  int l0 = (blk % (LL / 16)) * 16;
  int tid = threadIdx.x;
  __shared__ float tile[16][CC + 1];
  __shared__ float rs[16][17], rs2[16][17];
  __shared__ float mu[16], rstd[16];
  int ci2 = tid & 15, li2 = tid >> 4;
  const float* mb = mo + (size_t)(b * LL + l0) * CC;
  #pragma unroll
  for (int c0 = 0; c0 < CC; c0 += 16)
    tile[li2][c0 + ci2] = mb[(size_t)li2 * CC + c0 + ci2];
  __syncthreads();
  int li = tid & 15, ci = tid >> 4;
  float s = 0.f, s2 = 0.f;
  #pragma unroll
  for (int j = 0; j < 16; ++j) {
    float v = tile[li][ci * 16 + j];
    s += v; s2 += v * v;
  }
  rs[li][ci] = s; rs2[li][ci] = s2;
  __syncthreads();
  if (ci == 0) {
    float a = 0.f, a2 = 0.f;
    #pragma unroll
    for (int j = 0; j < 16; ++j) { a += rs[li][j]; a2 += rs2[li][j]; }
    float m = a * (1.f / CC);
    float var = a2 * (1.f / CC) - m * m;
    mu[li] = m; rstd[li] = rsqrtf(var + 1e-5f);
  }
  __syncthreads();
  int wli = tid & 15, wci = tid >> 4;
  const float* xb = x + (size_t)b * CC * LL;
  float* ob = out + (size_t)b * CC * LL;
  #pragma unroll
  for (int c0 = 0; c0 < CC; c0 += 16) {
    int c = c0 + wci;
    size_t idx = (size_t)c * LL + l0 + wli;
    float v = tile[wli][c];
    ob[idx] = xb[idx] + (v - mu[wli]) * rstd[wli] * w[c] + bias[c];
  }
}

extern "C" void kernel_launch(void* const* d_in, const int* in_sizes, int n_in,
                              void* d_out, int out_size, void* d_ws, size_t ws_size,
                              hipStream_t stream) {
  const float* x         = (const float*)d_in[0];
  const float* ln1_w     = (const float*)d_in[1];
  const float* ln1_b     = (const float*)d_in[2];
  const float* ln2_w     = (const float*)d_in[3];
  const float* ln2_b     = (const float*)d_in[4];
  const float* in_proj_w = (const float*)d_in[5];
  const float* conv_w    = (const float*)d_in[6];
  const float* conv_b    = (const float*)d_in[7];
  const float* x_proj_w  = (const float*)d_in[8];
  const float* dt_proj_w = (const float*)d_in[9];
  const float* dt_proj_b = (const float*)d_in[10];
  const float* A_log     = (const float*)d_in[11];
  const float* Dv        = (const float*)d_in[12];
  const float* out_proj_w= (const float*)d_in[13];

  char* wsp = (char*)d_ws;
  size_t off = 0;
  auto alloc = [&](size_t bytes) -> void* {
    void* p = wsp + off;
    off += (bytes + 255) & ~(size_t)255;
    return p;
  };
  float* xz   = (float*)alloc((size_t)NL * 1024 * 4);
  float* xc   = (float*)alloc((size_t)NL * DI * 4);
  float* proj = (float*)alloc((size_t)NL * NPROJ * 4);
  float* dtb  = (float*)alloc((size_t)NL * DI * 4);
  float* hend = (float*)alloc((size_t)BB * G_CHUNK * DI * 16 * 4);
  float* h0   = (float*)alloc((size_t)BB * G_CHUNK * DI * 16 * 4);
  float* sdt  = (float*)alloc((size_t)BB * G_CHUNK * DI * 4);
  float* mo   = (float*)alloc((size_t)NL * CC * 4);
  __hip_bfloat16* hbf  = (__hip_bfloat16*)alloc((size_t)NL * CC * 2);
  __hip_bfloat16* ybf  = (__hip_bfloat16*)alloc((size_t)NL * DI * 2);
  __hip_bfloat16* xcb  = (__hip_bfloat16*)alloc((size_t)NL * DI * 2);
  __hip_bfloat16* w1b  = (__hip_bfloat16*)alloc((size_t)1024 * 256 * 2);
  __hip_bfloat16* w2b  = (__hip_bfloat16*)alloc((size_t)256 * 512 * 2);
  __hip_bfloat16* xpwb = (__hip_bfloat16*)alloc((size_t)NPROJ * DI * 2);

  ln1_kernel<<<NL / 16, 256, 0, stream>>>(x, ln1_w, ln1_b, hbf);
  convert_w<<<(1024 * 256 + 256 * 512 + NPROJ * DI + 255) / 256, 256, 0, stream>>>(
      in_proj_w, out_proj_w, x_proj_w, w1b, w2b, xpwb);
  gemm_bf16<128, 128><<<dim3(1024 / 128, NL / 128), 256, 0, stream>>>(
      (const short*)hbf, (const short*)w1b, xz, NL, 1024, 256);
  conv_silu_kernel<<<NL, 512, 0, stream>>>(xz, conv_w, conv_b, xc, xcb);
  xproj_mfma<<<NL / 64, 256, 0, stream>>>((const short*)xcb, (const short*)xpwb, proj);
  dt_kernel<<<NL, 512, 0, stream>>>(proj, dt_proj_w, dt_proj_b, dtb);
  scan_passA<<<dim3(G_CHUNK, BB), 512, 0, stream>>>(dtb, xc, proj, A_log, hend, sdt);
  scan_combine<<<BB * DI * DS / 256, 256, 0, stream>>>(hend, sdt, A_log, h0);
  scan_passB<<<dim3(G_CHUNK, BB), 512, 0, stream>>>(dtb, xc, xz, proj, A_log, Dv, h0, ybf);
  gemm_bf16<128, 64><<<dim3(256 / 64, NL / 128), 256, 0, stream>>>(
      (const short*)ybf, (const short*)w2b, mo, NL, 256, 512);
  ln2_res_kernel<<<NL / 16, 256, 0, stream>>>(mo, x, ln2_w, ln2_b, (float*)d_out);
}